// Round 10
// baseline (188.585 us; speedup 1.0000x reference)
//
#include <hip/hip_runtime.h>
#include <math.h>

// smooth_step constants: LOW = pi/2 - pi/8, ramp width TW = pi/4
#define LOW_F   1.1780972450961724f
#define INV_TW  1.2732395447351628f   // 4/pi
#define WP_K    7.639437268410977f    // 6 * INV_TW  (dw/dtheta = 6 t (1-t) / TW)

typedef float floatx4 __attribute__((ext_vector_type(4)));

// Branchless acos, Cephes single-precision asin core (~1-2 ulp).
__device__ __forceinline__ float fast_acos(float x) {
    float s = __builtin_fabsf(x);
    bool big = s > 0.5f;
    float z = big ? fmaf(-0.5f, s, 0.5f) : x * x;
    float r = big ? __builtin_amdgcn_sqrtf(z) : s;
    float p = fmaf(z, 4.2163199048e-2f, 2.4181311049e-2f);
    p = fmaf(z, p, 4.5470025998e-2f);
    p = fmaf(z, p, 7.4953002686e-2f);
    p = fmaf(z, p, 1.6666752422e-1f);
    float asn = fmaf(r * z, p, r);
    float t2 = 2.0f * asn;
    float rb = (x >= 0.0f) ? t2 : (3.14159274f - t2);
    float rs = (x >= 0.0f) ? (1.57079637f - asn) : (1.57079637f + asn);
    return big ? rb : rs;
}

// Analytic velocity = -grad U  (calibrated R3/R7: absmax 0.50 vs threshold 2.04)
__device__ __forceinline__ void point_velocity(float x, float y, float z,
                                               float a, float b,
                                               float dx, float dy, float dz,
                                               float& vx, float& vy, float& vz) {
    float r2 = x * x + y * y + z * z;
    float r = __builtin_amdgcn_sqrtf(r2);
    float invr = __builtin_amdgcn_rcpf(r);
    float dot = (x * dx + y * dy + z * dz) * invr;
    dot = fminf(fmaxf(dot, -1.0f), 1.0f);
    float theta = fast_acos(dot);

    float t = (theta - LOW_F) * INV_TW;
    t = fminf(fmaxf(t, 0.0f), 1.0f);
    float w = t * t * (3.0f - 2.0f * t);
    float one_m_w = 1.0f - w;
    float wp = WP_K * t * (1.0f - t);              // dw/dtheta (0 outside ramp)

    float th2 = theta * theta;
    float k1 = fmaf(b * th2, one_m_w, a);          // a + b th^2 (1-w)

    float sin2 = fmaf(-dot, dot, 1.0f);            // 1 - dot^2
    float sinth = __builtin_amdgcn_sqrtf(fmaxf(sin2, 0.0f));
    float rcpsin = __builtin_amdgcn_rcpf(fmaxf(sinth, 1e-30f));
    float num = fmaf(2.0f * theta, one_m_w, -th2 * wp);  // 2 th (1-w) - th^2 w' ; ==0 at dot=+-1
    float k2 = (r * 0.5f * b) * num * rcpsin;

    float m = dot * invr;                          // dot / r
    float gx = fmaf(-m, x, dx);                    // d - dot * p_hat
    float gy = fmaf(-m, y, dy);
    float gz = fmaf(-m, z, dz);

    float ovx = fmaf(-k1, x, k2 * gx);
    float ovy = fmaf(-k1, y, k2 * gy);
    float ovz = fmaf(-k1, z, k2 * gz);

    bool origin = (r2 == 0.0f);
    vx = origin ? 0.0f : ovx;
    vy = origin ? 0.0f : ovy;
    vz = origin ? 0.0f : ovz;
}

// Persistent grid-stride with 1-deep branchless software pipeline.
// __launch_bounds__(256,2) relaxes VGPR pressure (R3/R5/R7 all compiled to 28
// VGPR -> compiler serialized the load batches; here the double buffer fits).
// Prefetch addresses are clamped (cndmask, no branch) so loads always issue
// before the current iteration's compute, keeping ~3KB/wave in flight.
extern "C" __global__ void __launch_bounds__(256, 2)
canyon3d_pipe_kernel(const float* __restrict__ xyz,
                     const float* __restrict__ a_param,
                     const float* __restrict__ b_param,
                     const float* __restrict__ dir,
                     float* __restrict__ out,
                     int B) {
    int nquad = B >> 2;
    int tid = blockIdx.x * blockDim.x + threadIdx.x;
    int stride = gridDim.x * blockDim.x;

    float a = fminf(fmaxf(a_param[0], 0.0f), 20.0f);
    float b = fminf(fmaxf(b_param[0], 0.0f), 20.0f);
    float dx = dir[0], dy = dir[1], dz = dir[2];

    const floatx4* in4 = (const floatx4*)xyz;
    floatx4* out4 = (floatx4*)out;

    if (tid < nquad) {
        int q = tid;
        floatx4 A  = in4[3 * q + 0];
        floatx4 Bv = in4[3 * q + 1];
        floatx4 C  = in4[3 * q + 2];
        int qn = q + stride;
        for (;;) {
            // branchless prefetch: clamp index so the loads are unconditional
            int qp = (qn < nquad) ? qn : q;
            floatx4 An = in4[3 * qp + 0];
            floatx4 Bn = in4[3 * qp + 1];
            floatx4 Cn = in4[3 * qp + 2];

            float o0, o1, o2, o3, o4, o5, o6, o7, o8, o9, o10, o11;
            point_velocity(A.x, A.y, A.z,   a, b, dx, dy, dz, o0, o1, o2);
            point_velocity(A.w, Bv.x, Bv.y, a, b, dx, dy, dz, o3, o4, o5);
            point_velocity(Bv.z, Bv.w, C.x, a, b, dx, dy, dz, o6, o7, o8);
            point_velocity(C.y, C.z, C.w,   a, b, dx, dy, dz, o9, o10, o11);

            floatx4 O0 = {o0, o1, o2, o3};
            floatx4 O1 = {o4, o5, o6, o7};
            floatx4 O2 = {o8, o9, o10, o11};
            out4[3 * q + 0] = O0;
            out4[3 * q + 1] = O1;
            out4[3 * q + 2] = O2;

            if (qn >= nquad) break;
            q = qn; qn += stride;
            A = An; Bv = Bn; C = Cn;
        }
    }

    // tail points (B % 4)
    int done = nquad << 2;
    int rem = B - done;
    if (tid < rem) {
        int i = done + tid;
        float x = xyz[3 * i], y = xyz[3 * i + 1], z = xyz[3 * i + 2];
        float vx, vy, vz;
        point_velocity(x, y, z, a, b, dx, dy, dz, vx, vy, vz);
        out[3 * i] = vx; out[3 * i + 1] = vy; out[3 * i + 2] = vz;
    }
}

extern "C" void kernel_launch(void* const* d_in, const int* in_sizes, int n_in,
                              void* d_out, int out_size, void* d_ws, size_t ws_size,
                              hipStream_t stream) {
    const float* xyz = (const float*)d_in[0];
    const float* a_param = (const float*)d_in[1];
    const float* b_param = (const float*)d_in[2];
    const float* dir = (const float*)d_in[3];
    float* out = (float*)d_out;

    int B = in_sizes[0] / 3;
    int nquad = (B + 3) / 4;
    // 1024 persistent blocks = 4 blocks/CU (16 waves) resident; 8 quads/thread.
    int blocks = 1024;
    int maxBlocks = (nquad + 255) / 256;
    if (blocks > maxBlocks) blocks = maxBlocks > 0 ? maxBlocks : 1;
    canyon3d_pipe_kernel<<<dim3(blocks), dim3(256), 0, stream>>>(xyz, a_param, b_param, dir, out, B);
}

// Round 12
// 185.968 us; speedup vs baseline: 1.0141x; 1.0141x over previous
//
#include <hip/hip_runtime.h>
#include <math.h>

// smooth_step constants: LOW = pi/2 - pi/8, ramp width TW = pi/4
#define LOW_F   1.1780972450961724f
#define INV_TW  1.2732395447351628f   // 4/pi
#define WP_K    7.639437268410977f    // 6 * INV_TW  (dw/dtheta = 6 t (1-t) / TW)

typedef float floatx4 __attribute__((ext_vector_type(4)));

// Branchless acos, Cephes single-precision asin core (~1-2 ulp).
__device__ __forceinline__ float fast_acos(float x) {
    float s = __builtin_fabsf(x);
    bool big = s > 0.5f;
    float z = big ? fmaf(-0.5f, s, 0.5f) : x * x;
    float r = big ? __builtin_amdgcn_sqrtf(z) : s;
    float p = fmaf(z, 4.2163199048e-2f, 2.4181311049e-2f);
    p = fmaf(z, p, 4.5470025998e-2f);
    p = fmaf(z, p, 7.4953002686e-2f);
    p = fmaf(z, p, 1.6666752422e-1f);
    float asn = fmaf(r * z, p, r);
    float t2 = 2.0f * asn;
    float rb = (x >= 0.0f) ? t2 : (3.14159274f - t2);
    float rs = (x >= 0.0f) ? (1.57079637f - asn) : (1.57079637f + asn);
    return big ? rb : rs;
}

// Analytic velocity = -grad U  (calibrated R3/R7/R10: absmax 0.50 vs threshold 2.04)
__device__ __forceinline__ void point_velocity(float x, float y, float z,
                                               float a, float b,
                                               float dx, float dy, float dz,
                                               float& vx, float& vy, float& vz) {
    float r2 = x * x + y * y + z * z;
    float r = __builtin_amdgcn_sqrtf(r2);
    float invr = __builtin_amdgcn_rcpf(r);
    float dot = (x * dx + y * dy + z * dz) * invr;
    dot = fminf(fmaxf(dot, -1.0f), 1.0f);
    float theta = fast_acos(dot);

    float t = (theta - LOW_F) * INV_TW;
    t = fminf(fmaxf(t, 0.0f), 1.0f);
    float w = t * t * (3.0f - 2.0f * t);
    float one_m_w = 1.0f - w;
    float wp = WP_K * t * (1.0f - t);              // dw/dtheta (0 outside ramp)

    float th2 = theta * theta;
    float k1 = fmaf(b * th2, one_m_w, a);          // a + b th^2 (1-w)

    float sin2 = fmaf(-dot, dot, 1.0f);            // 1 - dot^2
    float sinth = __builtin_amdgcn_sqrtf(fmaxf(sin2, 0.0f));
    float rcpsin = __builtin_amdgcn_rcpf(fmaxf(sinth, 1e-30f));
    float num = fmaf(2.0f * theta, one_m_w, -th2 * wp);  // 2 th (1-w) - th^2 w' ; ==0 at dot=+-1
    float k2 = (r * 0.5f * b) * num * rcpsin;

    float m = dot * invr;                          // dot / r
    float gx = fmaf(-m, x, dx);                    // d - dot * p_hat
    float gy = fmaf(-m, y, dy);
    float gz = fmaf(-m, z, dz);

    float ovx = fmaf(-k1, x, k2 * gx);
    float ovy = fmaf(-k1, y, k2 * gy);
    float ovz = fmaf(-k1, z, k2 * gz);

    bool origin = (r2 == 0.0f);
    vx = origin ? 0.0f : ovx;
    vy = origin ? 0.0f : ovy;
    vz = origin ? 0.0f : ovz;
}

__device__ __forceinline__ void do_quad(floatx4 A, floatx4 Bv, floatx4 C,
                                        float a, float b,
                                        float dx, float dy, float dz,
                                        floatx4* __restrict__ out4, int q) {
    float o0, o1, o2, o3, o4, o5, o6, o7, o8, o9, o10, o11;
    point_velocity(A.x, A.y, A.z,   a, b, dx, dy, dz, o0, o1, o2);
    point_velocity(A.w, Bv.x, Bv.y, a, b, dx, dy, dz, o3, o4, o5);
    point_velocity(Bv.z, Bv.w, C.x, a, b, dx, dy, dz, o6, o7, o8);
    point_velocity(C.y, C.z, C.w,   a, b, dx, dy, dz, o9, o10, o11);
    floatx4 O0 = {o0, o1, o2, o3};
    floatx4 O1 = {o4, o5, o6, o7};
    floatx4 O2 = {o8, o9, o10, o11};
    out4[3 * q + 0] = O0;
    out4[3 * q + 1] = O1;
    out4[3 * q + 2] = O2;
}

// Straight-line 4-quad batch: all 12 float4 loads issued, then sched_barrier(0)
// statically pins them before any compute (the compiler CANNOT sink them, so
// 48+ VGPRs of loads are forced live -> 12KB/wave outstanding). The compiler's
// vmcnt counting then yields wait(9)/compute0/store0/wait(6)/compute1/... .
extern "C" __global__ void __launch_bounds__(256)
canyon3d_batch4_kernel(const float* __restrict__ xyz,
                       const float* __restrict__ a_param,
                       const float* __restrict__ b_param,
                       const float* __restrict__ dir,
                       float* __restrict__ out,
                       int B) {
    int nquad = B >> 2;
    int tid = blockIdx.x * blockDim.x + threadIdx.x;
    int stride = gridDim.x * blockDim.x;
    int bigstride = stride << 2;

    float a = fminf(fmaxf(a_param[0], 0.0f), 20.0f);
    float b = fminf(fmaxf(b_param[0], 0.0f), 20.0f);
    float dx = dir[0], dy = dir[1], dz = dir[2];

    const floatx4* in4 = (const floatx4*)xyz;
    floatx4* out4 = (floatx4*)out;

    for (int qb = tid; qb < nquad; qb += bigstride) {
        int q0 = qb;
        int q1 = qb + stride;
        int q2 = qb + 2 * stride;
        int q3 = qb + 3 * stride;
        bool v1 = q1 < nquad, v2 = q2 < nquad, v3 = q3 < nquad;
        int c1 = v1 ? q1 : q0;
        int c2 = v2 ? q2 : q0;
        int c3 = v3 ? q3 : q0;

        // 12 back-to-back loads (q0 is always valid)
        floatx4 A0 = in4[3 * q0 + 0], B0 = in4[3 * q0 + 1], C0 = in4[3 * q0 + 2];
        floatx4 A1 = in4[3 * c1 + 0], B1 = in4[3 * c1 + 1], C1 = in4[3 * c1 + 2];
        floatx4 A2 = in4[3 * c2 + 0], B2 = in4[3 * c2 + 1], C2 = in4[3 * c2 + 2];
        floatx4 A3 = in4[3 * c3 + 0], B3 = in4[3 * c3 + 1], C3 = in4[3 * c3 + 2];
        __builtin_amdgcn_sched_barrier(0);   // loads may not sink below this point

        do_quad(A0, B0, C0, a, b, dx, dy, dz, out4, q0);
        if (v1) do_quad(A1, B1, C1, a, b, dx, dy, dz, out4, q1);
        if (v2) do_quad(A2, B2, C2, a, b, dx, dy, dz, out4, q2);
        if (v3) do_quad(A3, B3, C3, a, b, dx, dy, dz, out4, q3);
    }

    // tail points (B % 4)
    int done = nquad << 2;
    int rem = B - done;
    if (tid < rem) {
        int i = done + tid;
        float x = xyz[3 * i], y = xyz[3 * i + 1], z = xyz[3 * i + 2];
        float vx, vy, vz;
        point_velocity(x, y, z, a, b, dx, dy, dz, vx, vy, vz);
        out[3 * i] = vx; out[3 * i + 1] = vy; out[3 * i + 2] = vz;
    }
}

extern "C" void kernel_launch(void* const* d_in, const int* in_sizes, int n_in,
                              void* d_out, int out_size, void* d_ws, size_t ws_size,
                              hipStream_t stream) {
    const float* xyz = (const float*)d_in[0];
    const float* a_param = (const float*)d_in[1];
    const float* b_param = (const float*)d_in[2];
    const float* dir = (const float*)d_in[3];
    float* out = (float*)d_out;

    int B = in_sizes[0] / 3;
    int nquad = (B + 3) / 4;
    // 2048 blocks x 256 thr x 4 quads = 2.097M quads = exactly nquad at B=8.39M
    int blocks = 2048;
    int maxBlocks = (nquad + 255) / 256;
    if (blocks > maxBlocks) blocks = maxBlocks > 0 ? maxBlocks : 1;
    canyon3d_batch4_kernel<<<dim3(blocks), dim3(256), 0, stream>>>(xyz, a_param, b_param, dir, out, B);
}